// Round 3
// baseline (1034.792 us; speedup 1.0000x reference)
//
#include <hip/hip_runtime.h>
#include <hip/hip_bf16.h>

typedef unsigned int u32;
typedef _Float16 f16;
typedef f16 f16x2 __attribute__((ext_vector_type(2)));

#define BB 64
#define LL 128
#define TT 64
#define NN 128
#define NM (NN*NN)   // 16384

__device__ __forceinline__ float sigf(float v) {
    return 1.0f / (1.0f + __expf(-v));
}

__device__ __forceinline__ float fdot2f(f16x2 wa, f16x2 xa, float ca) {
#if defined(__HIP_DEVICE_COMPILE__) && __has_builtin(__builtin_amdgcn_fdot2)
    return __builtin_amdgcn_fdot2(wa, xa, ca, false);
#else
    return ca + (float)wa[0] * (float)xa[0] + (float)wa[1] * (float)xa[1];
#endif
}

__device__ __forceinline__ float clip01(float v) {
    return fminf(fmaxf(v, 0.f), 1.f);
}

// ---------------------------------------------------------------------------
// Kernel A: wT2[tpi][nm] = pack_half2(sig(ntp[nm][2tpi]), sig(ntp[nm][2tpi+1]))
// 32 * 16384 u32 = 2 MB.
__global__ __launch_bounds__(256) void sig_transpose(const float* __restrict__ ntp,
                                                     u32* __restrict__ out) {
    __shared__ float lds[64 * 65];
    const int nm0 = blockIdx.x * 64;
    const int tid = threadIdx.x;
    #pragma unroll
    for (int it = 0; it < 16; ++it) {
        int idx = it * 256 + tid;
        int r = idx >> 6, c = idx & 63;
        lds[r * 65 + c] = sigf(ntp[(nm0 + r) * 64 + c]);
    }
    __syncthreads();
    #pragma unroll
    for (int it = 0; it < 8; ++it) {
        int o = it * 256 + tid;
        int tpi = o >> 6, r = o & 63;
        f16x2 h;
        h[0] = (f16)lds[r * 65 + 2 * tpi];
        h[1] = (f16)lds[r * 65 + 2 * tpi + 1];
        out[tpi * NM + nm0 + r] = __builtin_bit_cast(u32, h);
    }
}

// ---------------------------------------------------------------------------
// Kernel B: pack x to f16x2 t-pairs: xpk[b][s][tpi], 64*128*32 u32 = 1 MB.
__global__ __launch_bounds__(256) void prep_x(const float* __restrict__ x_all,
                                              u32* __restrict__ xpk) {
    const int idx = blockIdx.x * 256 + threadIdx.x;   // 0 .. 262143
    const int tpi = idx & 31;
    const int bs  = idx >> 5;                          // b*128 + s
    float2 xv = *reinterpret_cast<const float2*>(x_all + (size_t)bs * 64 + 2 * tpi);
    f16x2 h;
    h[0] = (f16)xv.x;
    h[1] = (f16)xv.y;
    xpk[idx] = __builtin_bit_cast(u32, h);
}

// ---------------------------------------------------------------------------
// Kernel C: npc[b][s][nm] = clip(sum_t ntpsig[nm][t] * x[b][s][t]), fp16.
// Grid: 1024 wgs x 256 threads; wg = (b, sgrp of 8 steps). Each wg sweeps the
// full 2 MB weight array once (L2-resident), amortized over 8 step-columns.
__global__ __launch_bounds__(256) void gemm_npc(const u32* __restrict__ wT2,
                                                const u32* __restrict__ xpk,
                                                ushort* __restrict__ npc) {
    __shared__ u32 xs[8][32];
    const int blk = blockIdx.x;
    const int b = blk >> 4, sgrp = blk & 15;
    const int tid = threadIdx.x;
    {
        int j = tid >> 5, tpi = tid & 31;
        int s = 1 + sgrp * 8 + j;
        xs[j][tpi] = (s < 128) ? xpk[(b * 128 + s) * 32 + tpi] : 0u;
    }
    __syncthreads();

    for (int blkn = 0; blkn < 8; ++blkn) {
        const int nm0 = blkn * 2048 + tid * 8;   // this thread's 8 nm slots
        float acc[8][8];                          // [step j][nm r]
        #pragma unroll
        for (int j = 0; j < 8; ++j)
            #pragma unroll
            for (int r = 0; r < 8; ++r) acc[j][r] = 0.f;

        #pragma unroll 2
        for (int tpi = 0; tpi < 32; ++tpi) {
            const u32* base = wT2 + tpi * NM + nm0;
            uint4 w0 = *reinterpret_cast<const uint4*>(base);
            uint4 w1 = *reinterpret_cast<const uint4*>(base + 4);
            u32 wv[8] = {w0.x, w0.y, w0.z, w0.w, w1.x, w1.y, w1.z, w1.w};
            u32 xr[8];
            #pragma unroll
            for (int j = 0; j < 8; ++j) xr[j] = xs[j][tpi];   // LDS broadcast
            #pragma unroll
            for (int r = 0; r < 8; ++r) {
                f16x2 w = __builtin_bit_cast(f16x2, wv[r]);
                #pragma unroll
                for (int j = 0; j < 8; ++j)
                    acc[j][r] = fdot2f(w, __builtin_bit_cast(f16x2, xr[j]), acc[j][r]);
            }
        }

        #pragma unroll
        for (int j = 0; j < 8; ++j) {
            int s = 1 + sgrp * 8 + j;
            if (s < 128) {
                u32 ow[4];
                #pragma unroll
                for (int q = 0; q < 4; ++q) {
                    f16x2 h;
                    h[0] = (f16)clip01(acc[j][2 * q]);
                    h[1] = (f16)clip01(acc[j][2 * q + 1]);
                    ow[q] = __builtin_bit_cast(u32, h);
                }
                uint4 ov; ov.x = ow[0]; ov.y = ow[1]; ov.z = ow[2]; ov.w = ow[3];
                *reinterpret_cast<uint4*>(npc + ((size_t)(b * 128 + s)) * NM + nm0) = ov;
            }
        }
    }
}

// ---------------------------------------------------------------------------
// Kernel D: sequential recursion. 64 wgs x 1024 threads; thread (n = tid>>3,
// sub = tid&7) owns 16 m's; 8-lane shfl reduce; depth-2 npc prefetch.
__global__ __launch_bounds__(1024) void recur(const float* __restrict__ x_all,
                                              const float* __restrict__ tp,
                                              const ushort* __restrict__ npc,
                                              float* __restrict__ outp) {
    __shared__ float prevbuf[2][NN];
    __shared__ float masks[LL];
    __shared__ float x0[TT];

    const int b = blockIdx.x;
    const int tid = threadIdx.x;

    if (tid < 64) x0[tid] = x_all[(size_t)b * (LL * TT) + tid];
    else if (tid < 192) {
        int s = tid - 64;
        masks[s] = x_all[(size_t)b * (LL * TT) + s * 64 + 63];
    }
    __syncthreads();

    if (tid < NN) {
        float a = 0.f;
        #pragma unroll 8
        for (int t = 0; t < TT; ++t)
            a += sigf(tp[tid * TT + t]) * x0[t];
        prevbuf[0][tid] = a;               // tpc, NOT clipped
    }
    __syncthreads();

    float out_r = prevbuf[0][0];           // out0 = tpc[:,0] (only tid0 uses)

    const int n = tid >> 3, sub = tid & 7, mb = sub * 16;
    const ushort* pb = npc + (size_t)b * 128 * NM + n * NN + mb;

    // prefetch pipeline: c = step s, nx = step s+1
    uint4 c0 = *reinterpret_cast<const uint4*>(pb + 1 * NM);
    uint4 c1 = *reinterpret_cast<const uint4*>(pb + 1 * NM + 8);
    uint4 n0 = *reinterpret_cast<const uint4*>(pb + 2 * NM);
    uint4 n1 = *reinterpret_cast<const uint4*>(pb + 2 * NM + 8);

    int p = 0;
    for (int s = 1; s <= 127; ++s) {
        uint4 f0 = n0, f1 = n1;
        if (s + 2 <= 127) {
            f0 = *reinterpret_cast<const uint4*>(pb + (s + 2) * NM);
            f1 = *reinterpret_cast<const uint4*>(pb + (s + 2) * NM + 8);
        }
        float4 p0 = *reinterpret_cast<const float4*>(&prevbuf[p][mb]);
        float4 p1 = *reinterpret_cast<const float4*>(&prevbuf[p][mb + 4]);
        float4 p2 = *reinterpret_cast<const float4*>(&prevbuf[p][mb + 8]);
        float4 p3 = *reinterpret_cast<const float4*>(&prevbuf[p][mb + 12]);
        float pv[16] = {p0.x, p0.y, p0.z, p0.w, p1.x, p1.y, p1.z, p1.w,
                        p2.x, p2.y, p2.z, p2.w, p3.x, p3.y, p3.z, p3.w};
        u32 cw[8] = {c0.x, c0.y, c0.z, c0.w, c1.x, c1.y, c1.z, c1.w};
        float sum = 0.f;
        #pragma unroll
        for (int q = 0; q < 8; ++q) {
            f16x2 h = __builtin_bit_cast(f16x2, cw[q]);
            sum = fmaf((float)h[0], pv[2 * q], sum);
            sum = fmaf((float)h[1], pv[2 * q + 1], sum);
        }
        sum += __shfl_xor(sum, 1);
        sum += __shfl_xor(sum, 2);
        sum += __shfl_xor(sum, 4);
        float c = 0.f;
        if (sub == 0) {
            c = clip01(sum);
            prevbuf[p ^ 1][n] = c;
        }
        if (tid == 0) {
            float mk = masks[s];
            out_r = out_r * mk + c * (1.f - mk);
        }
        __syncthreads();
        p ^= 1;
        c0 = n0; c1 = n1; n0 = f0; n1 = f1;
    }

    if (tid == 0) outp[b] = out_r;
}

// ---------------------------------------------------------------------------
// Fallback (round-2 passing kernel): fused recurrence, needs only 2 MB ws.
__global__ __launch_bounds__(1024) void grammar_fused(
    const float* __restrict__ x_all,
    const float* __restrict__ tp,
    const u32*  __restrict__ ntpT2,
    float* __restrict__ outp) {
    __shared__ float x_lds[LL * TT];
    __shared__ float prevbuf[2][NN];
    __shared__ u32 x2_lds[2][32];

    const int b = blockIdx.x;
    const int tid = threadIdx.x;
    const int lane16 = tid & 15;
    const int g = tid >> 4;
    const int mbase = lane16 * 8;

    const float* xb = x_all + b * (LL * TT);
    #pragma unroll
    for (int it = 0; it < 8; ++it) {
        int idx = it * 1024 + tid;
        x_lds[idx] = xb[idx];
    }
    __syncthreads();

    if (tid < NN) {
        float acc = 0.f;
        #pragma unroll 8
        for (int t = 0; t < TT; ++t)
            acc += sigf(tp[tid * TT + t]) * x_lds[t];
        prevbuf[0][tid] = acc;
    }
    __syncthreads();
    float out_r = 0.f;
    if (tid == 0) out_r = prevbuf[0][0];

    int p = 0;
    for (int i0 = 1; i0 < LL; i0 += 2) {
        const int ns = (LL - i0) >= 2 ? 2 : 1;
        if (tid < 64) {
            int s = tid >> 5, tpi = tid & 31;
            f16x2 h;
            if (s < ns) {
                h[0] = (f16)x_lds[(i0 + s) * TT + 2 * tpi];
                h[1] = (f16)x_lds[(i0 + s) * TT + 2 * tpi + 1];
            } else {
                h[0] = (f16)0.f; h[1] = (f16)0.f;
            }
            x2_lds[s][tpi] = __builtin_bit_cast(u32, h);
        }
        __syncthreads();

        float acc[2][2][8];
        #pragma unroll
        for (int k = 0; k < 2; ++k)
            #pragma unroll
            for (int s = 0; s < 2; ++s)
                #pragma unroll
                for (int j = 0; j < 8; ++j) acc[k][s][j] = 0.f;

        #pragma unroll 2
        for (int tpi = 0; tpi < 32; ++tpi) {
            f16x2 xv0 = __builtin_bit_cast(f16x2, x2_lds[0][tpi]);
            f16x2 xv1 = __builtin_bit_cast(f16x2, x2_lds[1][tpi]);
            const u32* base = ntpT2 + tpi * NM + 8 * tid;
            #pragma unroll
            for (int k = 0; k < 2; ++k) {
                uint4 w0 = *reinterpret_cast<const uint4*>(base + 8192 * k);
                uint4 w1 = *reinterpret_cast<const uint4*>(base + 8192 * k + 4);
                u32 wv[8] = {w0.x, w0.y, w0.z, w0.w, w1.x, w1.y, w1.z, w1.w};
                #pragma unroll
                for (int j = 0; j < 8; ++j) {
                    f16x2 w = __builtin_bit_cast(f16x2, wv[j]);
                    acc[k][0][j] = fdot2f(w, xv0, acc[k][0][j]);
                    acc[k][1][j] = fdot2f(w, xv1, acc[k][1][j]);
                }
            }
        }

        for (int s = 0; s < ns; ++s) {
            float4 pv0 = *reinterpret_cast<const float4*>(&prevbuf[p][mbase]);
            float4 pv1 = *reinterpret_cast<const float4*>(&prevbuf[p][mbase + 4]);
            float pvv[8] = {pv0.x, pv0.y, pv0.z, pv0.w, pv1.x, pv1.y, pv1.z, pv1.w};
            #pragma unroll
            for (int k = 0; k < 2; ++k) {
                float part = 0.f;
                #pragma unroll
                for (int j = 0; j < 8; ++j) {
                    float npcv = clip01(acc[k][s][j]);
                    part += npcv * pvv[j];
                }
                part += __shfl_xor(part, 1);
                part += __shfl_xor(part, 2);
                part += __shfl_xor(part, 4);
                part += __shfl_xor(part, 8);
                if (lane16 == 0) {
                    float c = clip01(part);
                    prevbuf[p ^ 1][g + 64 * k] = c;
                    if (tid == 0 && k == 0) {
                        float mask = x_lds[(i0 + s) * TT + 63];
                        out_r = out_r * mask + c * (1.f - mask);
                    }
                }
            }
            p ^= 1;
            __syncthreads();
        }
    }

    if (tid == 0) outp[b] = out_r;
}

// ---------------------------------------------------------------------------
extern "C" void kernel_launch(void* const* d_in, const int* in_sizes, int n_in,
                              void* d_out, int out_size, void* d_ws, size_t ws_size,
                              hipStream_t stream) {
    const float* input_tensor = (const float*)d_in[0];   // [64][128][64]
    const float* term_prod    = (const float*)d_in[1];   // [128][64]
    const float* nonterm_prod = (const float*)d_in[2];   // [128][128][64]
    float* outp = (float*)d_out;                         // [64]

    const size_t NPC_BYTES = (size_t)256 * 1024 * 1024;  // 64*128*16384 fp16
    const size_t W_BYTES   = (size_t)2 * 1024 * 1024;
    const size_t X_BYTES   = (size_t)1 * 1024 * 1024;

    if (ws_size >= NPC_BYTES + W_BYTES + X_BYTES) {
        ushort* npcbuf = (ushort*)d_ws;
        u32* wT2 = (u32*)((char*)d_ws + NPC_BYTES);
        u32* xpk = (u32*)((char*)d_ws + NPC_BYTES + W_BYTES);
        sig_transpose<<<256, 256, 0, stream>>>(nonterm_prod, wT2);
        prep_x<<<1024, 256, 0, stream>>>(input_tensor, xpk);
        gemm_npc<<<1024, 256, 0, stream>>>(wT2, xpk, npcbuf);
        recur<<<BB, 1024, 0, stream>>>(input_tensor, term_prod, npcbuf, outp);
    } else {
        u32* ntpT2 = (u32*)d_ws;
        sig_transpose<<<256, 256, 0, stream>>>(nonterm_prod, ntpT2);
        grammar_fused<<<BB, 1024, 0, stream>>>(input_tensor, term_prod, ntpT2, outp);
    }
}

// Round 4
// 341.246 us; speedup vs baseline: 3.0324x; 3.0324x over previous
//
#include <hip/hip_runtime.h>
#include <hip/hip_bf16.h>

typedef unsigned int u32;
typedef _Float16 f16;
typedef f16 f16x2 __attribute__((ext_vector_type(2)));

#define BB 64
#define LL 128
#define TT 64
#define NN 128
#define NM (NN*NN)   // 16384

__device__ __forceinline__ float sigf(float v) {
    return 1.0f / (1.0f + __expf(-v));
}

__device__ __forceinline__ float fdot2f(f16x2 wa, f16x2 xa, float ca) {
#if defined(__HIP_DEVICE_COMPILE__) && __has_builtin(__builtin_amdgcn_fdot2)
    return __builtin_amdgcn_fdot2(wa, xa, ca, false);
#else
    return ca + (float)wa[0] * (float)xa[0] + (float)wa[1] * (float)xa[1];
#endif
}

__device__ __forceinline__ float clip01(float v) {
    return fminf(fmaxf(v, 0.f), 1.f);
}

// ---------------------------------------------------------------------------
// Kernel A: wT2[tpi][nm] = pack_half2(sig(ntp[nm][2tpi]), sig(ntp[nm][2tpi+1]))
__global__ __launch_bounds__(256) void sig_transpose(const float* __restrict__ ntp,
                                                     u32* __restrict__ out) {
    __shared__ float lds[64 * 65];
    const int nm0 = blockIdx.x * 64;
    const int tid = threadIdx.x;
    #pragma unroll
    for (int it = 0; it < 16; ++it) {
        int idx = it * 256 + tid;
        int r = idx >> 6, c = idx & 63;
        lds[r * 65 + c] = sigf(ntp[(nm0 + r) * 64 + c]);
    }
    __syncthreads();
    #pragma unroll
    for (int it = 0; it < 8; ++it) {
        int o = it * 256 + tid;
        int tpi = o >> 6, r = o & 63;
        f16x2 h;
        h[0] = (f16)lds[r * 65 + 2 * tpi];
        h[1] = (f16)lds[r * 65 + 2 * tpi + 1];
        out[tpi * NM + nm0 + r] = __builtin_bit_cast(u32, h);
    }
}

// ---------------------------------------------------------------------------
// Kernel B: npc chunk GEMM. Grid = 64 * G wgs (G = ceil(ns/8)), 256 threads.
// wg (b, g) computes npc[slot][b][nm] = clip(sum_t sig_w[nm][t]*x[b][s][t])
// for its 8 steps s = s0 + g*8 + j, full nm sweep (weights 2MB, L2-resident).
// npc layout: [slot][b][nm] fp16, slot = s - s0.
__global__ __launch_bounds__(256) void gemm_npc(const u32* __restrict__ wT2,
                                                const float* __restrict__ x_all,
                                                ushort* __restrict__ npc,
                                                int s0, int ns, int G) {
    __shared__ u32 xs[8][32];
    const int b = blockIdx.x / G;
    const int g = blockIdx.x % G;
    const int tid = threadIdx.x;
    {
        int j = tid >> 5, tpi = tid & 31;
        int s = s0 + g * 8 + j;
        u32 val = 0u;
        if (s < s0 + ns) {
            float2 xv = *reinterpret_cast<const float2*>(
                x_all + ((size_t)b * LL + s) * TT + 2 * tpi);
            f16x2 h; h[0] = (f16)xv.x; h[1] = (f16)xv.y;
            val = __builtin_bit_cast(u32, h);
        }
        xs[j][tpi] = val;
    }
    __syncthreads();

    for (int blkn = 0; blkn < 8; ++blkn) {
        const int nm0 = blkn * 2048 + tid * 8;
        float acc[8][8];
        #pragma unroll
        for (int j = 0; j < 8; ++j)
            #pragma unroll
            for (int r = 0; r < 8; ++r) acc[j][r] = 0.f;

        #pragma unroll 2
        for (int tpi = 0; tpi < 32; ++tpi) {
            const u32* base = wT2 + tpi * NM + nm0;
            uint4 w0 = *reinterpret_cast<const uint4*>(base);
            uint4 w1 = *reinterpret_cast<const uint4*>(base + 4);
            u32 wv[8] = {w0.x, w0.y, w0.z, w0.w, w1.x, w1.y, w1.z, w1.w};
            u32 xr[8];
            #pragma unroll
            for (int j = 0; j < 8; ++j) xr[j] = xs[j][tpi];
            #pragma unroll
            for (int r = 0; r < 8; ++r) {
                f16x2 w = __builtin_bit_cast(f16x2, wv[r]);
                #pragma unroll
                for (int j = 0; j < 8; ++j)
                    acc[j][r] = fdot2f(w, __builtin_bit_cast(f16x2, xr[j]), acc[j][r]);
            }
        }

        #pragma unroll
        for (int j = 0; j < 8; ++j) {
            int s = s0 + g * 8 + j;
            if (s < s0 + ns) {
                int slot = g * 8 + j;
                u32 ow[4];
                #pragma unroll
                for (int q = 0; q < 4; ++q) {
                    f16x2 h;
                    h[0] = (f16)clip01(acc[j][2 * q]);
                    h[1] = (f16)clip01(acc[j][2 * q + 1]);
                    ow[q] = __builtin_bit_cast(u32, h);
                }
                uint4 ov; ov.x = ow[0]; ov.y = ow[1]; ov.z = ow[2]; ov.w = ow[3];
                *reinterpret_cast<uint4*>(
                    npc + ((size_t)slot * 64 + b) * NM + nm0) = ov;
            }
        }
    }
}

// ---------------------------------------------------------------------------
// Kernel C: sequential recursion over one chunk of ns steps.
// 64 wgs x 1024 threads; thread (n = tid>>3, sub = tid&7) owns 16 m's;
// 8-lane shfl reduce; depth-2 npc prefetch. State carried in global scratch.
__global__ __launch_bounds__(1024) void recur_chunk(const float* __restrict__ x_all,
                                                    const float* __restrict__ tp,
                                                    const ushort* __restrict__ npc,
                                                    float* __restrict__ prev_state,
                                                    float* __restrict__ out_state,
                                                    float* __restrict__ outp,
                                                    int s0, int ns,
                                                    int is_first, int is_last) {
    __shared__ float prevbuf[2][NN];
    __shared__ float masks[LL];
    __shared__ float x0[TT];

    const int b = blockIdx.x;
    const int tid = threadIdx.x;

    if (tid < ns) masks[tid] = x_all[(size_t)b * (LL * TT) + (s0 + tid) * TT + 63];
    if (is_first && tid >= 256 && tid < 320)
        x0[tid - 256] = x_all[(size_t)b * (LL * TT) + (tid - 256)];
    __syncthreads();

    if (is_first) {
        if (tid < NN) {
            float a = 0.f;
            #pragma unroll 8
            for (int t = 0; t < TT; ++t)
                a += sigf(tp[tid * TT + t]) * x0[t];
            prevbuf[0][tid] = a;               // tpc, NOT clipped
        }
    } else {
        if (tid < NN) prevbuf[0][tid] = prev_state[b * NN + tid];
    }
    __syncthreads();

    float out_r = is_first ? prevbuf[0][0] : out_state[b];

    const int n = tid >> 3, sub = tid & 7, mb = sub * 16;
    const ushort* pb = npc + (size_t)b * NM + (size_t)n * NN + mb;
    const size_t SS = (size_t)64 * NM;    // slot stride in halves

    uint4 c0 = *reinterpret_cast<const uint4*>(pb);
    uint4 c1 = *reinterpret_cast<const uint4*>(pb + 8);
    uint4 nx0, nx1;
    if (ns > 1) {
        nx0 = *reinterpret_cast<const uint4*>(pb + SS);
        nx1 = *reinterpret_cast<const uint4*>(pb + SS + 8);
    } else { nx0 = c0; nx1 = c1; }

    int p = 0;
    for (int sl = 0; sl < ns; ++sl) {
        uint4 f0 = nx0, f1 = nx1;
        if (sl + 2 < ns) {
            f0 = *reinterpret_cast<const uint4*>(pb + (size_t)(sl + 2) * SS);
            f1 = *reinterpret_cast<const uint4*>(pb + (size_t)(sl + 2) * SS + 8);
        }
        float4 p0 = *reinterpret_cast<const float4*>(&prevbuf[p][mb]);
        float4 p1 = *reinterpret_cast<const float4*>(&prevbuf[p][mb + 4]);
        float4 p2 = *reinterpret_cast<const float4*>(&prevbuf[p][mb + 8]);
        float4 p3 = *reinterpret_cast<const float4*>(&prevbuf[p][mb + 12]);
        float pv[16] = {p0.x, p0.y, p0.z, p0.w, p1.x, p1.y, p1.z, p1.w,
                        p2.x, p2.y, p2.z, p2.w, p3.x, p3.y, p3.z, p3.w};
        u32 cw[8] = {c0.x, c0.y, c0.z, c0.w, c1.x, c1.y, c1.z, c1.w};
        float sum = 0.f;
        #pragma unroll
        for (int q = 0; q < 8; ++q) {
            f16x2 h = __builtin_bit_cast(f16x2, cw[q]);
            sum = fmaf((float)h[0], pv[2 * q], sum);
            sum = fmaf((float)h[1], pv[2 * q + 1], sum);
        }
        sum += __shfl_xor(sum, 1);
        sum += __shfl_xor(sum, 2);
        sum += __shfl_xor(sum, 4);
        float c = 0.f;
        if (sub == 0) {
            c = clip01(sum);
            prevbuf[p ^ 1][n] = c;
        }
        if (tid == 0) {
            float mk = masks[sl];
            out_r = out_r * mk + c * (1.f - mk);
        }
        __syncthreads();
        p ^= 1;
        c0 = nx0; c1 = nx1; nx0 = f0; nx1 = f1;
    }

    if (is_last) {
        if (tid == 0) outp[b] = out_r;
    } else {
        if (tid < NN) prev_state[b * NN + tid] = prevbuf[p][tid];
        if (tid == 0) out_state[b] = out_r;
    }
}

// ---------------------------------------------------------------------------
// Fallback (known-passing round-2 kernel): fused recurrence, 2 MB ws.
__global__ __launch_bounds__(1024) void grammar_fused(
    const float* __restrict__ x_all,
    const float* __restrict__ tp,
    const u32*  __restrict__ ntpT2,
    float* __restrict__ outp) {
    __shared__ float x_lds[LL * TT];
    __shared__ float prevbuf[2][NN];
    __shared__ u32 x2_lds[2][32];

    const int b = blockIdx.x;
    const int tid = threadIdx.x;
    const int lane16 = tid & 15;
    const int g = tid >> 4;
    const int mbase = lane16 * 8;

    const float* xb = x_all + b * (LL * TT);
    #pragma unroll
    for (int it = 0; it < 8; ++it) {
        int idx = it * 1024 + tid;
        x_lds[idx] = xb[idx];
    }
    __syncthreads();

    if (tid < NN) {
        float acc = 0.f;
        #pragma unroll 8
        for (int t = 0; t < TT; ++t)
            acc += sigf(tp[tid * TT + t]) * x_lds[t];
        prevbuf[0][tid] = acc;
    }
    __syncthreads();
    float out_r = 0.f;
    if (tid == 0) out_r = prevbuf[0][0];

    int p = 0;
    for (int i0 = 1; i0 < LL; i0 += 2) {
        const int ns = (LL - i0) >= 2 ? 2 : 1;
        if (tid < 64) {
            int s = tid >> 5, tpi = tid & 31;
            f16x2 h;
            if (s < ns) {
                h[0] = (f16)x_lds[(i0 + s) * TT + 2 * tpi];
                h[1] = (f16)x_lds[(i0 + s) * TT + 2 * tpi + 1];
            } else {
                h[0] = (f16)0.f; h[1] = (f16)0.f;
            }
            x2_lds[s][tpi] = __builtin_bit_cast(u32, h);
        }
        __syncthreads();

        float acc[2][2][8];
        #pragma unroll
        for (int k = 0; k < 2; ++k)
            #pragma unroll
            for (int s = 0; s < 2; ++s)
                #pragma unroll
                for (int j = 0; j < 8; ++j) acc[k][s][j] = 0.f;

        #pragma unroll 2
        for (int tpi = 0; tpi < 32; ++tpi) {
            f16x2 xv0 = __builtin_bit_cast(f16x2, x2_lds[0][tpi]);
            f16x2 xv1 = __builtin_bit_cast(f16x2, x2_lds[1][tpi]);
            const u32* base = ntpT2 + tpi * NM + 8 * tid;
            #pragma unroll
            for (int k = 0; k < 2; ++k) {
                uint4 w0 = *reinterpret_cast<const uint4*>(base + 8192 * k);
                uint4 w1 = *reinterpret_cast<const uint4*>(base + 8192 * k + 4);
                u32 wv[8] = {w0.x, w0.y, w0.z, w0.w, w1.x, w1.y, w1.z, w1.w};
                #pragma unroll
                for (int j = 0; j < 8; ++j) {
                    f16x2 w = __builtin_bit_cast(f16x2, wv[j]);
                    acc[k][0][j] = fdot2f(w, xv0, acc[k][0][j]);
                    acc[k][1][j] = fdot2f(w, xv1, acc[k][1][j]);
                }
            }
        }

        for (int s = 0; s < ns; ++s) {
            float4 pv0 = *reinterpret_cast<const float4*>(&prevbuf[p][mbase]);
            float4 pv1 = *reinterpret_cast<const float4*>(&prevbuf[p][mbase + 4]);
            float pvv[8] = {pv0.x, pv0.y, pv0.z, pv0.w, pv1.x, pv1.y, pv1.z, pv1.w};
            #pragma unroll
            for (int k = 0; k < 2; ++k) {
                float part = 0.f;
                #pragma unroll
                for (int j = 0; j < 8; ++j) {
                    float npcv = clip01(acc[k][s][j]);
                    part += npcv * pvv[j];
                }
                part += __shfl_xor(part, 1);
                part += __shfl_xor(part, 2);
                part += __shfl_xor(part, 4);
                part += __shfl_xor(part, 8);
                if (lane16 == 0) {
                    float c = clip01(part);
                    prevbuf[p ^ 1][g + 64 * k] = c;
                    if (tid == 0 && k == 0) {
                        float mask = x_lds[(i0 + s) * TT + 63];
                        out_r = out_r * mask + c * (1.f - mask);
                    }
                }
            }
            p ^= 1;
            __syncthreads();
        }
    }

    if (tid == 0) outp[b] = out_r;
}

// ---------------------------------------------------------------------------
extern "C" void kernel_launch(void* const* d_in, const int* in_sizes, int n_in,
                              void* d_out, int out_size, void* d_ws, size_t ws_size,
                              hipStream_t stream) {
    const float* input_tensor = (const float*)d_in[0];   // [64][128][64]
    const float* term_prod    = (const float*)d_in[1];   // [128][64]
    const float* nonterm_prod = (const float*)d_in[2];   // [128][128][64]
    float* outp = (float*)d_out;                         // [64]

    const size_t MB = 1024 * 1024;
    const size_t W_BYTES  = 2 * MB;                      // packed weights
    const size_t ST_BYTES = 64 * 1024;                   // prev/out state
    const size_t STEP_BYTES = (size_t)64 * NM * sizeof(ushort);  // 2 MB/step

    if (ws_size >= W_BYTES + ST_BYTES + 8 * STEP_BYTES) {
        size_t cap = (ws_size - W_BYTES - ST_BYTES) / STEP_BYTES;
        int C = (int)(cap > 127 ? 127 : cap);            // steps per chunk

        u32* wT2 = (u32*)d_ws;
        float* prev_state = (float*)((char*)d_ws + W_BYTES);
        float* out_state  = prev_state + 64 * NN;
        ushort* npcbuf = (ushort*)((char*)d_ws + W_BYTES + ST_BYTES);

        sig_transpose<<<256, 256, 0, stream>>>(nonterm_prod, wT2);

        int s0 = 1, first = 1;
        while (s0 < 128) {
            int ns = (128 - s0 < C) ? (128 - s0) : C;
            int G = (ns + 7) / 8;
            gemm_npc<<<64 * G, 256, 0, stream>>>(wT2, input_tensor, npcbuf, s0, ns, G);
            int last = (s0 + ns >= 128) ? 1 : 0;
            recur_chunk<<<BB, 1024, 0, stream>>>(input_tensor, term_prod, npcbuf,
                                                 prev_state, out_state, outp,
                                                 s0, ns, first, last);
            first = 0;
            s0 += ns;
        }
    } else {
        u32* ntpT2 = (u32*)d_ws;
        sig_transpose<<<256, 256, 0, stream>>>(nonterm_prod, ntpT2);
        grammar_fused<<<BB, 1024, 0, stream>>>(input_tensor, term_prod, ntpT2, outp);
    }
}

// Round 5
// 190.394 us; speedup vs baseline: 5.4350x; 1.7923x over previous
//
#include <hip/hip_runtime.h>
#include <hip/hip_bf16.h>

typedef unsigned int u32;
typedef unsigned char u8;
typedef _Float16 f16;
typedef f16 f16x2 __attribute__((ext_vector_type(2)));
typedef short s16x8 __attribute__((ext_vector_type(8)));
typedef float f32x4 __attribute__((ext_vector_type(4)));

#define BB 64
#define LL 128
#define TT 64
#define NN 128
#define NM (NN*NN)   // 16384

__device__ __forceinline__ float sigf(float v) {
    return 1.0f / (1.0f + __expf(-v));
}

__device__ __forceinline__ float clip01(float v) {
    return fminf(fmaxf(v, 0.f), 1.f);
}

__device__ __forceinline__ u32 f2bf(float f) {   // f32 -> bf16 bits (RNE)
    u32 u = __builtin_bit_cast(u32, f);
    return (u + 0x7fffu + ((u >> 16) & 1u)) >> 16;
}

__device__ __forceinline__ float fdot2f(f16x2 wa, f16x2 xa, float ca) {
#if defined(__HIP_DEVICE_COMPILE__) && __has_builtin(__builtin_amdgcn_fdot2)
    return __builtin_amdgcn_fdot2(wa, xa, ca, false);
#else
    return ca + (float)wa[0] * (float)xa[0] + (float)wa[1] * (float)xa[1];
#endif
}

// ---------------------------------------------------------------------------
// pack_w: sigmoid(ntp) -> bf16 A-fragment order for mfma_f32_16x16x32_bf16.
// A-tile (i, khalf h): lane l holds A[row=l&15][k = h*32 + (l>>4)*8 + e], e=0..7.
// wpk slot g = (i*2+h)*64 + l holds 8 bf16 (16 B). Total 2 MB.
__global__ __launch_bounds__(256) void pack_w(const float* __restrict__ ntp,
                                              ushort* __restrict__ wpk) {
    const int g = blockIdx.x * 256 + threadIdx.x;   // 0..131071
    const int l = g & 63, h = (g >> 6) & 1, i = g >> 7;
    const int row = i * 16 + (l & 15);
    const int t0 = h * 32 + ((l >> 4) << 3);
    const float* src = ntp + row * 64 + t0;
    float4 f0 = *reinterpret_cast<const float4*>(src);
    float4 f1 = *reinterpret_cast<const float4*>(src + 4);
    float v[8] = {f0.x, f0.y, f0.z, f0.w, f1.x, f1.y, f1.z, f1.w};
    u32 o[4];
    #pragma unroll
    for (int q = 0; q < 4; ++q)
        o[q] = f2bf(sigf(v[2 * q])) | (f2bf(sigf(v[2 * q + 1])) << 16);
    uint4 ov; ov.x = o[0]; ov.y = o[1]; ov.z = o[2]; ov.w = o[3];
    *reinterpret_cast<uint4*>(wpk + (size_t)g * 8) = ov;
}

// ---------------------------------------------------------------------------
// pack_x: x -> bf16 B-fragment order. B-tile (b, stile j, khalf h): lane l holds
// B[k = h*32 + (l>>4)*8 + e][col = l&15], col = s-16*j; B[k][s] = x[b][s][t=k].
__global__ __launch_bounds__(256) void pack_x(const float* __restrict__ x_all,
                                              ushort* __restrict__ xpk) {
    const int g = blockIdx.x * 256 + threadIdx.x;   // 0..65535
    const int l = g & 63, h = (g >> 6) & 1, j = (g >> 7) & 7, b = g >> 10;
    const int s = j * 16 + (l & 15);
    const int t0 = h * 32 + ((l >> 4) << 3);
    const float* src = x_all + ((size_t)b * LL + s) * TT + t0;
    float4 f0 = *reinterpret_cast<const float4*>(src);
    float4 f1 = *reinterpret_cast<const float4*>(src + 4);
    float v[8] = {f0.x, f0.y, f0.z, f0.w, f1.x, f1.y, f1.z, f1.w};
    u32 o[4];
    #pragma unroll
    for (int q = 0; q < 4; ++q)
        o[q] = f2bf(v[2 * q]) | (f2bf(v[2 * q + 1]) << 16);
    uint4 ov; ov.x = o[0]; ov.y = o[1]; ov.z = o[2]; ov.w = o[3];
    *reinterpret_cast<uint4*>(xpk + (size_t)g * 8) = ov;
}

// ---------------------------------------------------------------------------
// gemm_mfma: npc[s][b][nm] (u8) = round(255*clip01(sum_t sigW[nm][t]*x[b][s][t])).
// Grid 512 wgs = (b in 64) x (nb in 8); 4 waves; wave handles 32 nm-tiles.
// B-frags for all 8 s-tiles held in registers; A-frags loaded per tile.
// C/D layout (measured, m89): col=lane&15 (s), row=(lane>>4)*4+reg (nm).
__global__ __launch_bounds__(256) void gemm_mfma(const ushort* __restrict__ wpk,
                                                 const ushort* __restrict__ xpk,
                                                 u8* __restrict__ npc) {
    const int b = blockIdx.x >> 3;
    const int nb = blockIdx.x & 7;
    const int wv = threadIdx.x >> 6, l = threadIdx.x & 63;

    uint4 xf[8][2];
    #pragma unroll
    for (int j = 0; j < 8; ++j)
        #pragma unroll
        for (int h = 0; h < 2; ++h)
            xf[j][h] = *reinterpret_cast<const uint4*>(
                xpk + (size_t)(((b * 8 + j) * 2 + h) * 64 + l) * 8);

    const int c = l & 15, r0 = (l >> 4) * 4;

    for (int it = 0; it < 32; ++it) {
        const int i = nb * 128 + wv * 32 + it;       // nm-tile index 0..1023
        uint4 a0 = *reinterpret_cast<const uint4*>(wpk + (size_t)((i * 2 + 0) * 64 + l) * 8);
        uint4 a1 = *reinterpret_cast<const uint4*>(wpk + (size_t)((i * 2 + 1) * 64 + l) * 8);
        f32x4 acc[8];
        const f32x4 z = {0.f, 0.f, 0.f, 0.f};
        #pragma unroll
        for (int j = 0; j < 8; ++j)
            acc[j] = __builtin_amdgcn_mfma_f32_16x16x32_bf16(
                __builtin_bit_cast(s16x8, a0), __builtin_bit_cast(s16x8, xf[j][0]), z, 0, 0, 0);
        #pragma unroll
        for (int j = 0; j < 8; ++j)
            acc[j] = __builtin_amdgcn_mfma_f32_16x16x32_bf16(
                __builtin_bit_cast(s16x8, a1), __builtin_bit_cast(s16x8, xf[j][1]), acc[j], 0, 0, 0);

        #pragma unroll
        for (int j = 0; j < 8; ++j) {
            u32 w = 0;
            #pragma unroll
            for (int r = 0; r < 4; ++r) {
                float q = clip01(acc[j][r]) * 255.f + 0.5f;
                w |= ((u32)q) << (8 * r);
            }
            const int s = j * 16 + c;
            *reinterpret_cast<u32*>(npc + (((size_t)(s * 64 + b)) << 14) + i * 16 + r0) = w;
        }
    }
}

// ---------------------------------------------------------------------------
// recur2: sequential recursion, u8 npc, f16 prev, depth-3 register prefetch,
// raw-barrier (lgkmcnt-only) so vmem prefetches survive across steps.
__global__ __launch_bounds__(1024) void recur2(const float* __restrict__ x_all,
                                               const float* __restrict__ tp,
                                               const u8* __restrict__ npc,
                                               float* __restrict__ outp) {
    __shared__ __align__(16) ushort prevh[2][NN];
    __shared__ float masks[LL];
    __shared__ float x0[TT];

    const int b = blockIdx.x, tid = threadIdx.x;
    if (tid < 128) masks[tid] = x_all[(size_t)b * 8192 + tid * 64 + 63];
    else if (tid < 192) x0[tid - 128] = x_all[(size_t)b * 8192 + (tid - 128)];
    __syncthreads();

    float out_r = 0.f;
    if (tid < 128) {
        float a = 0.f;
        #pragma unroll 8
        for (int t = 0; t < TT; ++t)
            a += sigf(tp[tid * TT + t]) * x0[t];
        f16 ha = (f16)a;
        prevh[0][tid] = __builtin_bit_cast(ushort, ha);
        if (tid == 0) out_r = a;               // out0 = tpc[0], exact fp32
    }
    __syncthreads();

    const int n = tid >> 3, sub = tid & 7;
    const u8* base = npc + (size_t)b * NM + n * NN + sub * 16;

    uint4 c0 = *reinterpret_cast<const uint4*>(base + (size_t)1 * 1048576);
    uint4 c1 = *reinterpret_cast<const uint4*>(base + (size_t)2 * 1048576);
    uint4 c2 = *reinterpret_cast<const uint4*>(base + (size_t)3 * 1048576);

    int p = 0;
    for (int s = 1; s <= 127; ++s) {
        const int sp = (s + 3 <= 127) ? (s + 3) : 127;
        uint4 f = *reinterpret_cast<const uint4*>(base + (size_t)sp * 1048576);

        uint4 ph0 = *reinterpret_cast<const uint4*>(
            reinterpret_cast<const char*>(&prevh[p][0]) + sub * 32);
        uint4 ph1 = *reinterpret_cast<const uint4*>(
            reinterpret_cast<const char*>(&prevh[p][0]) + sub * 32 + 16);

        u32 cw[4] = {c0.x, c0.y, c0.z, c0.w};
        u32 pw[8] = {ph0.x, ph0.y, ph0.z, ph0.w, ph1.x, ph1.y, ph1.z, ph1.w};
        float sum = 0.f;
        #pragma unroll
        for (int q = 0; q < 8; ++q) {
            f16x2 hp = __builtin_bit_cast(f16x2, pw[q]);
            u32 wb = (cw[q >> 1] >> ((q & 1) * 16)) & 0xffffu;
            sum = fmaf((float)(wb & 255u), (float)hp[0], sum);
            sum = fmaf((float)(wb >> 8), (float)hp[1], sum);
        }
        sum *= (1.0f / 255.0f);
        sum += __shfl_xor(sum, 1);
        sum += __shfl_xor(sum, 2);
        sum += __shfl_xor(sum, 4);
        float cc = clip01(sum);
        if (sub == 0) {
            f16 hc = (f16)cc;
            prevh[p ^ 1][n] = __builtin_bit_cast(ushort, hc);
        }
        if (tid == 0) {
            float mk = masks[s];
            out_r = out_r * mk + cc * (1.f - mk);
        }
        __builtin_amdgcn_sched_barrier(0);
        asm volatile("s_waitcnt lgkmcnt(0)");
        __builtin_amdgcn_s_barrier();
        __builtin_amdgcn_sched_barrier(0);
        p ^= 1;
        c0 = c1; c1 = c2; c2 = f;
    }

    if (tid == 0) outp[b] = out_r;
}

// ---------------------------------------------------------------------------
// Fallback (known-passing round-2 kernel): fused recurrence, 2 MB ws.
__global__ __launch_bounds__(256) void sig_transpose(const float* __restrict__ ntp,
                                                     u32* __restrict__ out) {
    __shared__ float lds[64 * 65];
    const int nm0 = blockIdx.x * 64;
    const int tid = threadIdx.x;
    #pragma unroll
    for (int it = 0; it < 16; ++it) {
        int idx = it * 256 + tid;
        int r = idx >> 6, c = idx & 63;
        lds[r * 65 + c] = sigf(ntp[(nm0 + r) * 64 + c]);
    }
    __syncthreads();
    #pragma unroll
    for (int it = 0; it < 8; ++it) {
        int o = it * 256 + tid;
        int tpi = o >> 6, r = o & 63;
        f16x2 h;
        h[0] = (f16)lds[r * 65 + 2 * tpi];
        h[1] = (f16)lds[r * 65 + 2 * tpi + 1];
        out[tpi * NM + nm0 + r] = __builtin_bit_cast(u32, h);
    }
}

__global__ __launch_bounds__(1024) void grammar_fused(
    const float* __restrict__ x_all,
    const float* __restrict__ tp,
    const u32*  __restrict__ ntpT2,
    float* __restrict__ outp) {
    __shared__ float x_lds[LL * TT];
    __shared__ float prevbuf[2][NN];
    __shared__ u32 x2_lds[2][32];

    const int b = blockIdx.x;
    const int tid = threadIdx.x;
    const int lane16 = tid & 15;
    const int g = tid >> 4;
    const int mbase = lane16 * 8;

    const float* xb = x_all + b * (LL * TT);
    #pragma unroll
    for (int it = 0; it < 8; ++it) {
        int idx = it * 1024 + tid;
        x_lds[idx] = xb[idx];
    }
    __syncthreads();

    if (tid < NN) {
        float acc = 0.f;
        #pragma unroll 8
        for (int t = 0; t < TT; ++t)
            acc += sigf(tp[tid * TT + t]) * x_lds[t];
        prevbuf[0][tid] = acc;
    }
    __syncthreads();
    float out_r = 0.f;
    if (tid == 0) out_r = prevbuf[0][0];

    int p = 0;
    for (int i0 = 1; i0 < LL; i0 += 2) {
        const int ns = (LL - i0) >= 2 ? 2 : 1;
        if (tid < 64) {
            int s = tid >> 5, tpi = tid & 31;
            f16x2 h;
            if (s < ns) {
                h[0] = (f16)x_lds[(i0 + s) * TT + 2 * tpi];
                h[1] = (f16)x_lds[(i0 + s) * TT + 2 * tpi + 1];
            } else {
                h[0] = (f16)0.f; h[1] = (f16)0.f;
            }
            x2_lds[s][tpi] = __builtin_bit_cast(u32, h);
        }
        __syncthreads();

        float acc[2][2][8];
        #pragma unroll
        for (int k = 0; k < 2; ++k)
            #pragma unroll
            for (int s = 0; s < 2; ++s)
                #pragma unroll
                for (int j = 0; j < 8; ++j) acc[k][s][j] = 0.f;

        #pragma unroll 2
        for (int tpi = 0; tpi < 32; ++tpi) {
            f16x2 xv0 = __builtin_bit_cast(f16x2, x2_lds[0][tpi]);
            f16x2 xv1 = __builtin_bit_cast(f16x2, x2_lds[1][tpi]);
            const u32* base = ntpT2 + tpi * NM + 8 * tid;
            #pragma unroll
            for (int k = 0; k < 2; ++k) {
                uint4 w0 = *reinterpret_cast<const uint4*>(base + 8192 * k);
                uint4 w1 = *reinterpret_cast<const uint4*>(base + 8192 * k + 4);
                u32 wv[8] = {w0.x, w0.y, w0.z, w0.w, w1.x, w1.y, w1.z, w1.w};
                #pragma unroll
                for (int j = 0; j < 8; ++j) {
                    f16x2 w = __builtin_bit_cast(f16x2, wv[j]);
                    acc[k][0][j] = fdot2f(w, xv0, acc[k][0][j]);
                    acc[k][1][j] = fdot2f(w, xv1, acc[k][1][j]);
                }
            }
        }

        for (int s = 0; s < ns; ++s) {
            float4 pv0 = *reinterpret_cast<const float4*>(&prevbuf[p][mbase]);
            float4 pv1 = *reinterpret_cast<const float4*>(&prevbuf[p][mbase + 4]);
            float pvv[8] = {pv0.x, pv0.y, pv0.z, pv0.w, pv1.x, pv1.y, pv1.z, pv1.w};
            #pragma unroll
            for (int k = 0; k < 2; ++k) {
                float part = 0.f;
                #pragma unroll
                for (int j = 0; j < 8; ++j) {
                    float npcv = clip01(acc[k][s][j]);
                    part += npcv * pvv[j];
                }
                part += __shfl_xor(part, 1);
                part += __shfl_xor(part, 2);
                part += __shfl_xor(part, 4);
                part += __shfl_xor(part, 8);
                if (lane16 == 0) {
                    float c = clip01(part);
                    prevbuf[p ^ 1][g + 64 * k] = c;
                    if (tid == 0 && k == 0) {
                        float mask = x_lds[(i0 + s) * TT + 63];
                        out_r = out_r * mask + c * (1.f - mask);
                    }
                }
            }
            p ^= 1;
            __syncthreads();
        }
    }

    if (tid == 0) outp[b] = out_r;
}

// ---------------------------------------------------------------------------
extern "C" void kernel_launch(void* const* d_in, const int* in_sizes, int n_in,
                              void* d_out, int out_size, void* d_ws, size_t ws_size,
                              hipStream_t stream) {
    const float* input_tensor = (const float*)d_in[0];   // [64][128][64]
    const float* term_prod    = (const float*)d_in[1];   // [128][64]
    const float* nonterm_prod = (const float*)d_in[2];   // [128][128][64]
    float* outp = (float*)d_out;                         // [64]

    const size_t MB = 1024 * 1024;
    const size_t NPC_BYTES = 128 * MB;   // 128 s x 64 b x 16384 nm, u8
    const size_t WPK_BYTES = 2 * MB;     // bf16 A-frags
    const size_t XPK_BYTES = 1 * MB;     // bf16 B-frags

    if (ws_size >= NPC_BYTES + WPK_BYTES + XPK_BYTES + MB) {
        u8* npcbuf  = (u8*)d_ws;
        ushort* wpk = (ushort*)((char*)d_ws + NPC_BYTES);
        ushort* xpk = (ushort*)((char*)d_ws + NPC_BYTES + WPK_BYTES);
        pack_w<<<512, 256, 0, stream>>>(nonterm_prod, wpk);
        pack_x<<<256, 256, 0, stream>>>(input_tensor, xpk);
        gemm_mfma<<<512, 256, 0, stream>>>(wpk, xpk, npcbuf);
        recur2<<<BB, 1024, 0, stream>>>(input_tensor, term_prod, npcbuf, outp);
    } else {
        u32* ntpT2 = (u32*)d_ws;
        sig_transpose<<<256, 256, 0, stream>>>(nonterm_prod, ntpT2);
        grammar_fused<<<BB, 1024, 0, stream>>>(input_tensor, term_prod, ntpT2, outp);
    }
}